// Round 14
// baseline (4570.447 us; speedup 1.0000x reference)
//
#include <hip/hip_runtime.h>

// FPS: B=64, N=32768, C=3, S=1024. One block per batch.
//
// Round-14: chunk-granular exact culling. Cloud is counting-sorted by 512
// fine cells (8^3) into d_ws as (x,y,z,idbits); the sorted array is cut
// into 512 fixed 64-point chunks (one point per lane). Prologue computes
// per-chunk AABBs from the actual member points. Per step:
//   * dirty test per chunk (waves 0-7, lane<->chunk): lb2(p, chunk AABB)
//     >= bmax*1.000004 -> skip (validated R11-R13, absmax=0: skip implies
//     every member's d >= its min_d, so fminf is a bit-exact no-op and the
//     cached chunk key stays valid). 8 ballot words, no atomics.
//   * dirty chunk scan = ONE coalesced float4 load (1 pt/lane), fma dist,
//     LDS min_d RMW (slot-indexed, conflict-free), one 6-level u64-key
//     butterfly; winner lane (key==bk, keys unique) writes key+coords.
//     1-deep lookahead overlaps next chunk's load with current butterfly.
//   * phase B: waves 0-7 butterfly 64 chunk keys (+chunk idx) -> 8 keys;
//     scalar 7-compare fold; winner coords from LDS. No global loads in
//     the serial chain.
// Keys: u64 (val_bits<<32 | 0xFFFFFFFF-idx): max = max val, tie -> min
// original index (= first occurrence). d = fma(dz,dz, fma(dx,dx, dy*dy)).

typedef unsigned long long u64;
typedef unsigned int u32;

#define FPS_N   32768
#define FPS_S   1024
#define FPS_NT  1024
#define NCH     512            // 64-point chunks
#define NCELL9  512            // 8x8x8 sort cells
#define PPT     (FPS_N / FPS_NT)

__device__ __forceinline__ int bin8(float v) {
    int i = (int)(v * 8.0f);
    i = i < 0 ? 0 : (i > 7 ? 7 : i);
    if (v < (float)i * 0.125f) --i;
    if (v >= (float)(i + 1) * 0.125f) ++i;
    i = i < 0 ? 0 : (i > 7 ? 7 : i);
    return i;
}

__global__ __launch_bounds__(FPS_NT) void FPSModel_80753975099708_kernel(
    const float* __restrict__ x,   // [B, N, 3]
    float* __restrict__ out_pts,   // [B, S, 3]
    float* __restrict__ out_idx,   // [B, S] (indices as float values)
    float4* __restrict__ ws4)      // [B][N] cell-sorted (x,y,z,idbits)
{
#pragma clang fp contract(off)
    const int b = blockIdx.x;
    const int t = threadIdx.x;
    const int w = t >> 6;
    const int lane = t & 63;
    const float* __restrict__ xb = x + (size_t)b * FPS_N * 3;
    float* __restrict__ op = out_pts + (size_t)b * FPS_S * 3;
    float* __restrict__ oi = out_idx + (size_t)b * FPS_S;
    float4* __restrict__ srt = ws4 + (size_t)b * FPS_N;

    __shared__ float mind[FPS_N];                       // 131072 B
    __shared__ float alox[NCH], aloy[NCH], aloz[NCH];   // chunk AABB lo
    __shared__ float ahix[NCH], ahiy[NCH], ahiz[NCH];   // chunk AABB hi
    __shared__ u64  ckey[NCH];                          // chunk max key
    __shared__ float cwx[NCH], cwy[NCH], cwz[NCH];      // chunk winner coords
    __shared__ u64  dmask[8];                           // dirty bitmask
    __shared__ u64  wkey[8];
    __shared__ u32  wchunk[8];
    __shared__ u32  cellStart[NCELL9 + 1];
    __shared__ u32  cellCur[NCELL9];

    // ---- Prologue: counting sort by fine cell ----
    if (t < NCELL9) cellCur[t] = 0;
    __syncthreads();

#pragma unroll
    for (int k = 0; k < PPT; ++k) {
        const int i = k * FPS_NT + t;
        mind[i] = __int_as_float(0x7f800000);           // +inf
        const float gx = xb[3 * i], gy = xb[3 * i + 1], gz = xb[3 * i + 2];
        const int c = (bin8(gx) << 6) | (bin8(gy) << 3) | bin8(gz);
        atomicAdd(&cellCur[c], 1u);
    }
    __syncthreads();
    if (t == 0) {
        u32 acc = 0;
        for (int c = 0; c < NCELL9; ++c) { cellStart[c] = acc; acc += cellCur[c]; }
        cellStart[NCELL9] = acc;
    }
    __syncthreads();
    if (t < NCELL9) cellCur[t] = cellStart[t];
    __syncthreads();
#pragma unroll
    for (int k = 0; k < PPT; ++k) {
        const int i = k * FPS_NT + t;
        const float gx = xb[3 * i], gy = xb[3 * i + 1], gz = xb[3 * i + 2];
        const int c = (bin8(gx) << 6) | (bin8(gy) << 3) | bin8(gz);
        const u32 slot = atomicAdd(&cellCur[c], 1u);
        float4 q;
        q.x = gx; q.y = gy; q.z = gz; q.w = __uint_as_float((u32)i);
        srt[slot] = q;
    }
    __syncthreads();                                    // srt final

    // ---- Prologue: per-chunk AABB from actual points; init keys ----
    for (int c = w; c < NCH; c += 16) {
        const float4 q = srt[(c << 6) + lane];
        float mnx = q.x, mny = q.y, mnz = q.z;
        float mxx = q.x, mxy = q.y, mxz = q.z;
#pragma unroll
        for (int o = 32; o; o >>= 1) {
            mnx = fminf(mnx, __shfl_xor(mnx, o));
            mny = fminf(mny, __shfl_xor(mny, o));
            mnz = fminf(mnz, __shfl_xor(mnz, o));
            mxx = fmaxf(mxx, __shfl_xor(mxx, o));
            mxy = fmaxf(mxy, __shfl_xor(mxy, o));
            mxz = fmaxf(mxz, __shfl_xor(mxz, o));
        }
        if (lane == 0) {
            alox[c] = mnx; aloy[c] = mny; aloz[c] = mnz;
            ahix[c] = mxx; ahiy[c] = mxy; ahiz[c] = mxz;
            ckey[c] = 0x7f80000000000000ULL;            // +inf -> dirty at s=1
        }
    }

    // ---- Seed: point 0 ----
    float px = xb[0], py = xb[1], pz = xb[2];
    if (t == 0) {
        oi[0] = 0.0f;
        op[0] = px; op[1] = py; op[2] = pz;
    }
    __syncthreads();

    for (int s = 1; s < FPS_S; ++s) {
        // ---- dirty test per chunk (waves 0-7) ----
        if (w < 8) {
            const int c = (w << 6) | lane;
            const float bmax = __uint_as_float((u32)(ckey[c] >> 32));
            const float ax = fmaxf(fmaxf(alox[c] - px, px - ahix[c]), 0.0f);
            const float ay = fmaxf(fmaxf(aloy[c] - py, py - ahiy[c]), 0.0f);
            const float az = fmaxf(fmaxf(aloz[c] - pz, pz - ahiz[c]), 0.0f);
            const float lb2 = ax * ax + ay * ay + az * az;
            const bool dirty = !(lb2 >= bmax * 1.000004f);
            const u64 mk = __ballot(dirty);
            if (lane == 0) dmask[w] = mk;
        }
        __syncthreads();                                // B1: masks ready

        // ---- scan dirty chunks, round-robin by global rank J ----
        auto PROCESS = [&](int c, float4 q) {
            const int slot = (c << 6) + lane;
            const float dx = q.x - px;
            const float dy = q.y - py;
            const float dz = q.z - pz;
            const float d = __builtin_fmaf(dz, dz,
                             __builtin_fmaf(dx, dx, dy * dy));
            const float m = fminf(mind[slot], d);
            mind[slot] = m;
            const u64 key = ((u64)__float_as_uint(m) << 32) |
                            (u64)(0xFFFFFFFFu - __float_as_uint(q.w));
            u64 bk = key;
#pragma unroll
            for (int o = 32; o; o >>= 1) {
                const u64 ok = __shfl_xor((unsigned long long)bk, o);
                if (ok > bk) bk = ok;
            }
            if (key == bk) {                            // unique winner lane
                ckey[c] = bk;
                cwx[c] = q.x; cwy[c] = q.y; cwz[c] = q.z;
            }
        };

        int J = 0, cPrev = -1;
        float4 qPrev;
        for (int w8 = 0; w8 < 8; ++w8) {
            u64 m = dmask[w8];
            while (m) {
                const int bit = __ffsll((unsigned long long)m) - 1;
                m &= m - 1;
                if ((J & 15) == w) {
                    const int c = (w8 << 6) | bit;
                    const float4 qNew = srt[(c << 6) + lane]; // in flight...
                    if (cPrev >= 0) PROCESS(cPrev, qPrev);    // ...during this
                    qPrev = qNew; cPrev = c;
                }
                ++J;
            }
        }
        if (cPrev >= 0) PROCESS(cPrev, qPrev);
        __syncthreads();                                // B2: ckey/cw final

        // ---- phase B1: waves 0-7 fold 64 chunk keys each ----
        if (w < 8) {
            const int c0 = (w << 6) | lane;
            u64 kk = ckey[c0];
            u32 cc = (u32)c0;
#pragma unroll
            for (int o = 32; o; o >>= 1) {
                const u64 ok = __shfl_xor((unsigned long long)kk, o);
                const u32 oc = (u32)__shfl_xor((int)cc, o);
                if (ok > kk) { kk = ok; cc = oc; }
            }
            if (lane == 0) { wkey[w] = kk; wchunk[w] = cc; }
        }
        __syncthreads();                                // B3: wkey ready

        // ---- phase B2: scalar fold of 8, winner coords from LDS ----
        u64 fk = wkey[0];
        u32 fc = wchunk[0];
#pragma unroll
        for (int j = 1; j < 8; ++j) {
            const u64 kk = wkey[j];
            if (kk > fk) { fk = kk; fc = wchunk[j]; }
        }
        const int cur = (int)(0xFFFFFFFFu - (u32)(fk & 0xFFFFFFFFull));
        px = cwx[fc]; py = cwy[fc]; pz = cwz[fc];

        if (t == 0) {
            oi[s] = (float)cur;
            op[(size_t)s * 3 + 0] = px;
            op[(size_t)s * 3 + 1] = py;
            op[(size_t)s * 3 + 2] = pz;
        }
    }
}

extern "C" void kernel_launch(void* const* d_in, const int* in_sizes, int n_in,
                              void* d_out, int out_size, void* d_ws, size_t ws_size,
                              hipStream_t stream) {
    const float* x = (const float*)d_in[0];
    const int B = in_sizes[0] / (FPS_N * 3);

    float* out_pts = (float*)d_out;
    float* out_idx = out_pts + (size_t)B * FPS_S * 3;
    float4* ws4 = (float4*)d_ws;                        // B*32768*16 = 33.5 MB

    hipLaunchKernelGGL(FPSModel_80753975099708_kernel,
                       dim3(B), dim3(FPS_NT), 0, stream,
                       x, out_pts, out_idx, ws4);
}